// Round 1
// baseline (984.056 us; speedup 1.0000x reference)
//
#include <hip/hip_runtime.h>
#include <stdint.h>
#include <stddef.h>

// GINE layer, MI355X. Design notes:
// - All three GEMMs use mfma_f32_16x16x32_bf16 (threshold = 2% of ref absmax,
//   bf16-tolerant). No LDS anywhere: weights are pre-swizzled per-launch into
//   MFMA B-frag order (bf16) in ws; waves load B-frags coalesced from L2.
// - Scatter-add aggregation uses f32 global atomics (102.4M dword atomics) --
//   measuring this round whether it dominates.
// - BN stats: per-block column partials + atomics, tiny finalize kernels.

#define NN 50000
#define EE 800000
#define DD 128
#define DE 64
#define H1 256

typedef __attribute__((ext_vector_type(8))) short short8;
typedef __attribute__((ext_vector_type(4))) float floatx4;

__device__ __forceinline__ short f2bf(float f) {
    union { float f; uint32_t u; } v; v.f = f;
    return (short)((v.u + 0x7FFFu + ((v.u >> 16) & 1u)) >> 16);  // RNE
}

// ---- swizzle weight matrix (row-major [ntiles*16][K] f32, i.e. B^T) into
// ---- MFMA B-frag order: dst[((nt*KC+kc)*64 + lane)*8 + j] = bf16(src[n*K+k])
// ---- with n = nt*16 + (lane&15), k = kc*32 + (lane>>4)*8 + j
__global__ __launch_bounds__(256) void swz_kernel(const float* __restrict__ src,
                                                  short* __restrict__ dst,
                                                  int KC, int K, int total) {
    int idx = blockIdx.x * 256 + threadIdx.x;
    if (idx >= total) return;
    int j = idx & 7;
    int lane = (idx >> 3) & 63;
    int f = idx >> 9;
    int kc = f % KC;
    int nt = f / KC;
    int n = nt * 16 + (lane & 15);
    int k = kc * 32 + ((lane >> 4) & 3) * 8 + j;
    dst[idx] = f2bf(src[(size_t)n * K + k]);
}

// ---- edge kernel: msg = relu(x[src] + ea@We^T + be); atomicAdd into agg[dst]
// Per wave: 16-edge groups. A-frags straight from global ea (f32->bf16),
// B-frags (We) held in registers (16 frags), 16 MFMAs per group.
#define EDGE_GPW 5
__global__ __launch_bounds__(256) void edge_kernel(
    const float* __restrict__ x,
    const int* __restrict__ ei,         // [2][EE], int32
    const float* __restrict__ ea,       // [EE][64]
    const short* __restrict__ weswz,    // 16 frags * 64 lanes * 8 bf16
    const float* __restrict__ be,
    float* __restrict__ agg)
{
    const int wave = threadIdx.x >> 6;
    const int lane = threadIdx.x & 63;
    const int l16 = lane & 15;
    const int q = lane >> 4;

    const short8* wp = (const short8*)weswz;
    short8 bfr[16];
#pragma unroll
    for (int f = 0; f < 16; ++f) bfr[f] = wp[f * 64 + lane];
    float bev[8];
#pragma unroll
    for (int t = 0; t < 8; ++t) bev[t] = be[t * 16 + l16];

    const int gbase = (blockIdx.x * 4 + wave) * EDGE_GPW;
    for (int g = 0; g < EDGE_GPW; ++g) {
        const int e0 = (gbase + g) * 16;
        const float* earow = ea + (size_t)(e0 + l16) * DE + q * 8;
        floatx4 p0 = *(const floatx4*)(earow);
        floatx4 p1 = *(const floatx4*)(earow + 4);
        floatx4 p2 = *(const floatx4*)(earow + 32);
        floatx4 p3 = *(const floatx4*)(earow + 36);
        short8 af0, af1;
#pragma unroll
        for (int j = 0; j < 4; ++j) {
            af0[j]     = f2bf(p0[j]);
            af0[j + 4] = f2bf(p1[j]);
            af1[j]     = f2bf(p2[j]);
            af1[j + 4] = f2bf(p3[j]);
        }
        floatx4 acc[8];
#pragma unroll
        for (int t = 0; t < 8; ++t) {
            floatx4 z = {0.f, 0.f, 0.f, 0.f};
            z = __builtin_amdgcn_mfma_f32_16x16x32_bf16(af0, bfr[t * 2], z, 0, 0, 0);
            acc[t] = __builtin_amdgcn_mfma_f32_16x16x32_bf16(af1, bfr[t * 2 + 1], z, 0, 0, 0);
        }
        // epilogue: row = q*4 + r (edge), col = l16 + 16*t (feature)
#pragma unroll
        for (int r = 0; r < 4; ++r) {
            const int e = e0 + q * 4 + r;
            const int s = ei[e];
            const int d = ei[EE + e];
            const float* xr = x + (size_t)s * DD;
            float* ar = agg + (size_t)d * DD;
#pragma unroll
            for (int t = 0; t < 8; ++t) {
                float v = acc[t][r] + bev[t] + xr[t * 16 + l16];
                v = fmaxf(v, 0.f);
                atomicAdd(&ar[t * 16 + l16], v);
            }
        }
    }
}

// ---- GEMM1: t1[N,256] = ((1+eps)*x + agg) @ W1^T + b1
#define G1_GPW 4
__global__ __launch_bounds__(256) void gemm1_kernel(
    const float* __restrict__ x,
    const float* __restrict__ agg,
    const float* __restrict__ epsp,
    const short* __restrict__ w1swz,
    const float* __restrict__ b1,
    float* __restrict__ t1)
{
    const int wave = threadIdx.x >> 6;
    const int lane = threadIdx.x & 63;
    const int l16 = lane & 15;
    const int q = lane >> 4;
    const float c1 = 1.0f + epsp[0];
    const short8* wp = (const short8*)w1swz;

    const int gbase = (blockIdx.x * 4 + wave) * G1_GPW;
    for (int g = 0; g < G1_GPW; ++g) {
        const int grp = gbase + g;
        if (grp >= NN / 16) break;
        const int n0 = grp * 16;
        const float* xr = x + (size_t)(n0 + l16) * DD + q * 8;
        const float* ar = agg + (size_t)(n0 + l16) * DD + q * 8;
        short8 af[4];
#pragma unroll
        for (int kc = 0; kc < 4; ++kc) {
            floatx4 xa = *(const floatx4*)(xr + kc * 32);
            floatx4 xb = *(const floatx4*)(xr + kc * 32 + 4);
            floatx4 aa = *(const floatx4*)(ar + kc * 32);
            floatx4 ab = *(const floatx4*)(ar + kc * 32 + 4);
#pragma unroll
            for (int j = 0; j < 4; ++j) {
                af[kc][j]     = f2bf(c1 * xa[j] + aa[j]);
                af[kc][j + 4] = f2bf(c1 * xb[j] + ab[j]);
            }
        }
#pragma unroll
        for (int nt = 0; nt < 16; ++nt) {
            floatx4 acc = {0.f, 0.f, 0.f, 0.f};
#pragma unroll
            for (int kc = 0; kc < 4; ++kc)
                acc = __builtin_amdgcn_mfma_f32_16x16x32_bf16(
                    af[kc], wp[(nt * 4 + kc) * 64 + lane], acc, 0, 0, 0);
            const float bb = b1[nt * 16 + l16];
#pragma unroll
            for (int r = 0; r < 4; ++r)
                t1[(size_t)(n0 + q * 4 + r) * H1 + nt * 16 + l16] = acc[r] + bb;
        }
    }
}

// ---- GEMM2: h2[N,128] = relu(t1*scale1 + shift1) @ W2^T + b2
#define G2_GPW 4
__global__ __launch_bounds__(256) void gemm2_kernel(
    const float* __restrict__ t1,
    const float* __restrict__ scale1,
    const float* __restrict__ shift1,
    const short* __restrict__ w2swz,
    const float* __restrict__ b2,
    float* __restrict__ h2)
{
    const int wave = threadIdx.x >> 6;
    const int lane = threadIdx.x & 63;
    const int l16 = lane & 15;
    const int q = lane >> 4;
    const short8* wp = (const short8*)w2swz;

    const int gbase = (blockIdx.x * 4 + wave) * G2_GPW;
    for (int g = 0; g < G2_GPW; ++g) {
        const int grp = gbase + g;
        if (grp >= NN / 16) break;
        const int n0 = grp * 16;
        const float* tr = t1 + (size_t)(n0 + l16) * H1 + q * 8;
        floatx4 acc[8];
#pragma unroll
        for (int nt = 0; nt < 8; ++nt) acc[nt] = (floatx4){0.f, 0.f, 0.f, 0.f};
#pragma unroll
        for (int kc = 0; kc < 8; ++kc) {
            floatx4 va = *(const floatx4*)(tr + kc * 32);
            floatx4 vb = *(const floatx4*)(tr + kc * 32 + 4);
            const int kb = kc * 32 + q * 8;
            short8 af;
#pragma unroll
            for (int j = 0; j < 4; ++j) {
                float u = va[j] * scale1[kb + j] + shift1[kb + j];
                af[j] = f2bf(fmaxf(u, 0.f));
                float w = vb[j] * scale1[kb + 4 + j] + shift1[kb + 4 + j];
                af[j + 4] = f2bf(fmaxf(w, 0.f));
            }
#pragma unroll
            for (int nt = 0; nt < 8; ++nt)
                acc[nt] = __builtin_amdgcn_mfma_f32_16x16x32_bf16(
                    af, wp[(nt * 8 + kc) * 64 + lane], acc[nt], 0, 0, 0);
        }
#pragma unroll
        for (int nt = 0; nt < 8; ++nt) {
            const float bb = b2[nt * 16 + l16];
#pragma unroll
            for (int r = 0; r < 4; ++r)
                h2[(size_t)(n0 + q * 4 + r) * DD + nt * 16 + l16] = acc[nt][r] + bb;
        }
    }
}

// ---- column stats: per-block partial sum/sumsq over rows, atomic combine
__global__ __launch_bounds__(256) void stats_kernel(const float* __restrict__ m,
                                                    int C, int rpb,
                                                    float* __restrict__ ssum,
                                                    float* __restrict__ ssumsq) {
    int c = threadIdx.x % C;
    int sub = threadIdx.x / C;
    int nsub = 256 / C;
    int rows = rpb / nsub;
    int r0 = blockIdx.x * rpb + sub * rows;
    float s = 0.f, s2 = 0.f;
    for (int i = 0; i < rows; ++i) {
        float v = m[(size_t)(r0 + i) * C + c];
        s += v;
        s2 += v * v;
    }
    atomicAdd(&ssum[c], s);
    atomicAdd(&ssumsq[c], s2);
}

__global__ void finalize_kernel(const float* __restrict__ ssum,
                                const float* __restrict__ ssumsq,
                                const float* __restrict__ gamma,
                                const float* __restrict__ beta,
                                float* __restrict__ scale,
                                float* __restrict__ shift, int C) {
    int c = threadIdx.x;
    if (c >= C) return;
    float mu = ssum[c] * (1.0f / NN);
    float var = ssumsq[c] * (1.0f / NN) - mu * mu;
    float rs = rsqrtf(var + 1e-5f);
    float sc = gamma[c] * rs;
    scale[c] = sc;
    shift[c] = beta[c] - mu * sc;
}

__global__ __launch_bounds__(256) void out_kernel(const float* __restrict__ h2,
                                                  const float* __restrict__ scale2,
                                                  const float* __restrict__ shift2,
                                                  float* __restrict__ out) {
    int idx = blockIdx.x * 256 + threadIdx.x;
    int base = idx * 4;
    if (base >= NN * DD) return;
    int c = base & (DD - 1);
    floatx4 v = *(const floatx4*)(h2 + base);
    floatx4 sc = *(const floatx4*)(scale2 + c);
    floatx4 sh = *(const floatx4*)(shift2 + c);
    floatx4 o;
#pragma unroll
    for (int j = 0; j < 4; ++j) o[j] = fmaxf(v[j] * sc[j] + sh[j], 0.f);
    *(floatx4*)(out + base) = o;
}

extern "C" void kernel_launch(void* const* d_in, const int* in_sizes, int n_in,
                              void* d_out, int out_size, void* d_ws, size_t ws_size,
                              hipStream_t stream) {
    const float* x     = (const float*)d_in[0];
    const int*   ei    = (const int*)d_in[1];    // int64 in ref canonicalizes to int32
    const float* ea    = (const float*)d_in[2];
    const float* We    = (const float*)d_in[3];
    const float* be    = (const float*)d_in[4];
    const float* W1    = (const float*)d_in[5];
    const float* b1    = (const float*)d_in[6];
    const float* g1    = (const float*)d_in[7];
    const float* beta1 = (const float*)d_in[8];
    const float* W2    = (const float*)d_in[9];
    const float* b2    = (const float*)d_in[10];
    const float* g2    = (const float*)d_in[11];
    const float* beta2 = (const float*)d_in[12];
    const float* epsp  = (const float*)d_in[13];

    float* ws      = (float*)d_ws;
    float* ssum1   = ws + 0;      // 256
    float* ssumsq1 = ws + 256;    // 256
    float* ssum2   = ws + 512;    // 128
    float* ssumsq2 = ws + 640;    // 128
    float* agg     = ws + 768;                       // [NN*DD]
    float* scale1  = agg + (size_t)NN * DD;          // 256
    float* shift1  = scale1 + 256;                   // 256
    float* scale2  = shift1 + 256;                   // 128
    float* shift2  = scale2 + 128;                   // 128
    float* t1      = shift2 + 128;                   // [NN*H1]
    float* h2      = t1 + (size_t)NN * H1;           // [NN*DD]
    short* weswz   = (short*)(h2 + (size_t)NN * DD); // 8192 bf16
    short* w1swz   = weswz + 8192;                   // 32768 bf16
    short* w2swz   = w1swz + 32768;                  // 32768 bf16

    // zero the stats partials + agg in one shot
    hipMemsetAsync(ws, 0, (768 + (size_t)NN * DD) * sizeof(float), stream);

    swz_kernel<<<dim3(32), 256, 0, stream>>>(We, weswz, 2, 64, 8192);
    swz_kernel<<<dim3(128), 256, 0, stream>>>(W1, w1swz, 4, 128, 32768);
    swz_kernel<<<dim3(128), 256, 0, stream>>>(W2, w2swz, 8, 256, 32768);

    edge_kernel<<<dim3(2500), 256, 0, stream>>>(x, ei, ea, weswz, be, agg);

    gemm1_kernel<<<dim3(196), 256, 0, stream>>>(x, agg, epsp, w1swz, b1, t1);
    stats_kernel<<<dim3(100), 256, 0, stream>>>(t1, H1, 500, ssum1, ssumsq1);
    finalize_kernel<<<dim3(1), 256, 0, stream>>>(ssum1, ssumsq1, g1, beta1, scale1, shift1, H1);

    gemm2_kernel<<<dim3(196), 256, 0, stream>>>(t1, scale1, shift1, w2swz, b2, h2);
    stats_kernel<<<dim3(100), 256, 0, stream>>>(h2, DD, 500, ssum2, ssumsq2);
    finalize_kernel<<<dim3(1), 128, 0, stream>>>(ssum2, ssumsq2, g2, beta2, scale2, shift2, DD);

    out_kernel<<<dim3(6250), 256, 0, stream>>>(h2, scale2, shift2, (float*)d_out);
}

// Round 2
// 699.460 us; speedup vs baseline: 1.4069x; 1.4069x over previous
//
#include <hip/hip_runtime.h>
#include <stdint.h>
#include <stddef.h>

// GINE layer, MI355X -- round 2.
// R1 post-mortem: edge_kernel 404us, bound by 102.4M f32 global atomics
// (WRITE_SIZE=400MB == exactly E*D*4 -> memory-side RMW write-through).
// R2: sort edges by dst (count/scan/pos), edge kernel writes bf16 msg rows
// to sorted slots (plain 256B writes), segment-reduce streams msg
// sequentially. BN stats fused into gemm epilogues. msg region reused for
// t1/h2. ws usage ~234.4 MB.

#define NN 50000
#define EE 800000
#define DD 128
#define DE 64
#define H1 256
#define NGRP 3125   // NN/16 exactly

typedef __attribute__((ext_vector_type(8))) short short8;
typedef __attribute__((ext_vector_type(4))) float floatx4;

__device__ __forceinline__ short f2bf(float f) {
    union { float f; uint32_t u; } v; v.f = f;
    return (short)((v.u + 0x7FFFu + ((v.u >> 16) & 1u)) >> 16);  // RNE
}
__device__ __forceinline__ float bf2f(uint16_t u) {
    union { uint32_t u; float f; } v; v.u = (uint32_t)u << 16;
    return v.f;
}

// ---- swizzle weight matrix (row-major [ntiles*16][K] f32, i.e. B^T) into
// ---- MFMA B-frag order (see R1 notes)
__global__ __launch_bounds__(256) void swz_kernel(const float* __restrict__ src,
                                                  short* __restrict__ dst,
                                                  int KC, int K, int total) {
    int idx = blockIdx.x * 256 + threadIdx.x;
    if (idx >= total) return;
    int j = idx & 7;
    int lane = (idx >> 3) & 63;
    int f = idx >> 9;
    int kc = f % KC;
    int nt = f / KC;
    int n = nt * 16 + (lane & 15);
    int k = kc * 32 + ((lane >> 4) & 3) * 8 + j;
    dst[idx] = f2bf(src[(size_t)n * K + k]);
}

// ---- sort-by-dst machinery ----
__global__ __launch_bounds__(256) void count_kernel(const int* __restrict__ ei,
                                                    uint32_t* __restrict__ deg) {
    int e = blockIdx.x * 256 + threadIdx.x;
    atomicAdd(&deg[ei[EE + e]], 1u);
}

__global__ __launch_bounds__(256) void scan1_kernel(const uint32_t* __restrict__ deg,
                                                    uint32_t* __restrict__ partial) {
    __shared__ uint32_t ls[256];
    int i = blockIdx.x * 256 + threadIdx.x;
    ls[threadIdx.x] = (i < NN) ? deg[i] : 0u;
    __syncthreads();
    for (int s = 128; s > 0; s >>= 1) {
        if (threadIdx.x < s) ls[threadIdx.x] += ls[threadIdx.x + s];
        __syncthreads();
    }
    if (threadIdx.x == 0) partial[blockIdx.x] = ls[0];
}

__global__ __launch_bounds__(256) void scan2_kernel(uint32_t* __restrict__ partial) {
    __shared__ uint32_t ls[196];
    if (threadIdx.x < 196) ls[threadIdx.x] = partial[threadIdx.x];
    __syncthreads();
    if (threadIdx.x == 0) {
        uint32_t run = 0;
        for (int i = 0; i < 196; ++i) { uint32_t t = ls[i]; ls[i] = run; run += t; }
    }
    __syncthreads();
    if (threadIdx.x < 196) partial[threadIdx.x] = ls[threadIdx.x];
}

__global__ __launch_bounds__(256) void scan3_kernel(const uint32_t* __restrict__ deg,
                                                    const uint32_t* __restrict__ partial,
                                                    uint32_t* __restrict__ base,
                                                    uint32_t* __restrict__ cursor) {
    __shared__ uint32_t ls[256];
    int i = blockIdx.x * 256 + threadIdx.x;
    uint32_t v = (i < NN) ? deg[i] : 0u;
    ls[threadIdx.x] = v;
    __syncthreads();
    for (int off = 1; off < 256; off <<= 1) {
        uint32_t t = (threadIdx.x >= off) ? ls[threadIdx.x - off] : 0u;
        __syncthreads();
        ls[threadIdx.x] += t;
        __syncthreads();
    }
    if (i < NN) {
        uint32_t b = partial[blockIdx.x] + ls[threadIdx.x] - v;  // exclusive
        base[i] = b;
        cursor[i] = b;
    }
}

__global__ __launch_bounds__(256) void pos_kernel(const int* __restrict__ ei,
                                                  uint32_t* __restrict__ cursor,
                                                  uint32_t* __restrict__ pos) {
    int e = blockIdx.x * 256 + threadIdx.x;
    pos[e] = atomicAdd(&cursor[ei[EE + e]], 1u);
}

// ---- edge kernel: msg_row[pos[e]] = bf16(relu(x[src] + ea@We^T + be))
#define EDGE_GPW 5
__global__ __launch_bounds__(256) void edge_kernel(
    const float* __restrict__ x,
    const int* __restrict__ ei,
    const float* __restrict__ ea,
    const short* __restrict__ weswz,
    const float* __restrict__ be,
    const uint32_t* __restrict__ pos,
    uint16_t* __restrict__ msg)
{
    const int wave = threadIdx.x >> 6;
    const int lane = threadIdx.x & 63;
    const int l16 = lane & 15;
    const int q = lane >> 4;

    const short8* wp = (const short8*)weswz;
    short8 bfr[16];
#pragma unroll
    for (int f = 0; f < 16; ++f) bfr[f] = wp[f * 64 + lane];
    float bev[8];
#pragma unroll
    for (int t = 0; t < 8; ++t) bev[t] = be[t * 16 + l16];

    const int gbase = (blockIdx.x * 4 + wave) * EDGE_GPW;
    for (int g = 0; g < EDGE_GPW; ++g) {
        const int e0 = (gbase + g) * 16;
        const float* earow = ea + (size_t)(e0 + l16) * DE + q * 8;
        floatx4 p0 = *(const floatx4*)(earow);
        floatx4 p1 = *(const floatx4*)(earow + 4);
        floatx4 p2 = *(const floatx4*)(earow + 32);
        floatx4 p3 = *(const floatx4*)(earow + 36);
        short8 af0, af1;
#pragma unroll
        for (int j = 0; j < 4; ++j) {
            af0[j]     = f2bf(p0[j]);
            af0[j + 4] = f2bf(p1[j]);
            af1[j]     = f2bf(p2[j]);
            af1[j + 4] = f2bf(p3[j]);
        }
        floatx4 acc[8];
#pragma unroll
        for (int t = 0; t < 8; ++t) {
            floatx4 z = {0.f, 0.f, 0.f, 0.f};
            z = __builtin_amdgcn_mfma_f32_16x16x32_bf16(af0, bfr[t * 2], z, 0, 0, 0);
            acc[t] = __builtin_amdgcn_mfma_f32_16x16x32_bf16(af1, bfr[t * 2 + 1], z, 0, 0, 0);
        }
        // epilogue: row = q*4 + r (edge), col = t*16 + l16 (feature)
#pragma unroll
        for (int r = 0; r < 4; ++r) {
            const int e = e0 + q * 4 + r;
            const int s = ei[e];
            const uint32_t p = pos[e];
            const float* xr = x + (size_t)s * DD;
            uint16_t* mrow = msg + (size_t)p * DD;
#pragma unroll
            for (int t = 0; t < 8; ++t) {
                float v = acc[t][r] + bev[t] + xr[t * 16 + l16];
                v = fmaxf(v, 0.f);
                mrow[t * 16 + l16] = (uint16_t)f2bf(v);
            }
        }
    }
}

// ---- segment reduce: h[n] = (1+eps)*x[n] + sum(msg rows of n)
__global__ __launch_bounds__(256) void reduce_kernel(
    const uint16_t* __restrict__ msg,
    const uint32_t* __restrict__ base,
    const uint32_t* __restrict__ deg,
    const float* __restrict__ x,
    const float* __restrict__ epsp,
    float* __restrict__ h)
{
    const int n = blockIdx.x * 4 + (threadIdx.x >> 6);
    const int lane = threadIdx.x & 63;
    const uint32_t* mp = (const uint32_t*)msg + (size_t)base[n] * 64 + lane;
    const uint32_t d = deg[n];
    float s0 = 0.f, s1 = 0.f;
    for (uint32_t i = 0; i < d; ++i) {
        uint32_t u = mp[(size_t)i * 64];
        s0 += bf2f((uint16_t)(u & 0xFFFFu));
        s1 += bf2f((uint16_t)(u >> 16));
    }
    const float c1 = 1.0f + epsp[0];
    const int idx = n * DD + lane * 2;
    float2 xv = *(const float2*)(x + idx);
    float2 o; o.x = c1 * xv.x + s0; o.y = c1 * xv.y + s1;
    *(float2*)(h + idx) = o;
}

// ---- GEMM1: t1[N,256] = h @ W1^T + b1, fused BN1 column stats
__global__ __launch_bounds__(256) void gemm1_kernel(
    const float* __restrict__ h,
    const short* __restrict__ w1swz,
    const float* __restrict__ b1,
    float* __restrict__ t1,
    float* __restrict__ gsum,
    float* __restrict__ gsq)
{
    __shared__ float ls[H1];
    __shared__ float ls2[H1];
    const int tid = threadIdx.x;
    ls[tid] = 0.f; ls2[tid] = 0.f;
    __syncthreads();

    const int wave = tid >> 6;
    const int lane = tid & 63;
    const int l16 = lane & 15;
    const int q = lane >> 4;
    const short8* wp = (const short8*)w1swz;

    const int grp = blockIdx.x * 4 + wave;
    if (grp < NGRP) {
        const int n0 = grp * 16;
        const float* hr = h + (size_t)(n0 + l16) * DD + q * 8;
        short8 af[4];
#pragma unroll
        for (int kc = 0; kc < 4; ++kc) {
            floatx4 va = *(const floatx4*)(hr + kc * 32);
            floatx4 vb = *(const floatx4*)(hr + kc * 32 + 4);
#pragma unroll
            for (int j = 0; j < 4; ++j) {
                af[kc][j]     = f2bf(va[j]);
                af[kc][j + 4] = f2bf(vb[j]);
            }
        }
#pragma unroll
        for (int nt = 0; nt < 16; ++nt) {
            floatx4 acc = {0.f, 0.f, 0.f, 0.f};
#pragma unroll
            for (int kc = 0; kc < 4; ++kc)
                acc = __builtin_amdgcn_mfma_f32_16x16x32_bf16(
                    af[kc], wp[(nt * 4 + kc) * 64 + lane], acc, 0, 0, 0);
            const float bb = b1[nt * 16 + l16];
            float s = 0.f, s2 = 0.f;
#pragma unroll
            for (int r = 0; r < 4; ++r) {
                float v = acc[r] + bb;
                t1[(size_t)(n0 + q * 4 + r) * H1 + nt * 16 + l16] = v;
                s += v; s2 += v * v;
            }
            atomicAdd(&ls[nt * 16 + l16], s);
            atomicAdd(&ls2[nt * 16 + l16], s2);
        }
    }
    __syncthreads();
    atomicAdd(&gsum[tid], ls[tid]);
    atomicAdd(&gsq[tid], ls2[tid]);
}

// ---- GEMM2: h2[N,128] = relu(t1*scale1+shift1) @ W2^T + b2, fused BN2 stats
__global__ __launch_bounds__(256) void gemm2_kernel(
    const float* __restrict__ t1,
    const float* __restrict__ scale1,
    const float* __restrict__ shift1,
    const short* __restrict__ w2swz,
    const float* __restrict__ b2,
    float* __restrict__ h2,
    float* __restrict__ gsum,
    float* __restrict__ gsq)
{
    __shared__ float ls[DD];
    __shared__ float ls2[DD];
    const int tid = threadIdx.x;
    if (tid < DD) { ls[tid] = 0.f; ls2[tid] = 0.f; }
    __syncthreads();

    const int wave = tid >> 6;
    const int lane = tid & 63;
    const int l16 = lane & 15;
    const int q = lane >> 4;
    const short8* wp = (const short8*)w2swz;

    const int grp = blockIdx.x * 4 + wave;
    if (grp < NGRP) {
        const int n0 = grp * 16;
        const float* tr = t1 + (size_t)(n0 + l16) * H1 + q * 8;
        floatx4 acc[8];
#pragma unroll
        for (int nt = 0; nt < 8; ++nt) acc[nt] = (floatx4){0.f, 0.f, 0.f, 0.f};
#pragma unroll
        for (int kc = 0; kc < 8; ++kc) {
            floatx4 va = *(const floatx4*)(tr + kc * 32);
            floatx4 vb = *(const floatx4*)(tr + kc * 32 + 4);
            const int kb = kc * 32 + q * 8;
            short8 af;
#pragma unroll
            for (int j = 0; j < 4; ++j) {
                float u = va[j] * scale1[kb + j] + shift1[kb + j];
                af[j] = f2bf(fmaxf(u, 0.f));
                float w = vb[j] * scale1[kb + 4 + j] + shift1[kb + 4 + j];
                af[j + 4] = f2bf(fmaxf(w, 0.f));
            }
#pragma unroll
            for (int nt = 0; nt < 8; ++nt)
                acc[nt] = __builtin_amdgcn_mfma_f32_16x16x32_bf16(
                    af, wp[(nt * 8 + kc) * 64 + lane], acc[nt], 0, 0, 0);
        }
#pragma unroll
        for (int nt = 0; nt < 8; ++nt) {
            const float bb = b2[nt * 16 + l16];
            float s = 0.f, s2 = 0.f;
#pragma unroll
            for (int r = 0; r < 4; ++r) {
                float v = acc[nt][r] + bb;
                h2[(size_t)(n0 + q * 4 + r) * DD + nt * 16 + l16] = v;
                s += v; s2 += v * v;
            }
            atomicAdd(&ls[nt * 16 + l16], s);
            atomicAdd(&ls2[nt * 16 + l16], s2);
        }
    }
    __syncthreads();
    if (tid < DD) {
        atomicAdd(&gsum[tid], ls[tid]);
        atomicAdd(&gsq[tid], ls2[tid]);
    }
}

__global__ void finalize_kernel(const float* __restrict__ ssum,
                                const float* __restrict__ ssumsq,
                                const float* __restrict__ gamma,
                                const float* __restrict__ beta,
                                float* __restrict__ scale,
                                float* __restrict__ shift, int C) {
    int c = threadIdx.x;
    if (c >= C) return;
    float mu = ssum[c] * (1.0f / NN);
    float var = ssumsq[c] * (1.0f / NN) - mu * mu;
    float rs = rsqrtf(var + 1e-5f);
    float sc = gamma[c] * rs;
    scale[c] = sc;
    shift[c] = beta[c] - mu * sc;
}

__global__ __launch_bounds__(256) void out_kernel(const float* __restrict__ h2,
                                                  const float* __restrict__ scale2,
                                                  const float* __restrict__ shift2,
                                                  float* __restrict__ out) {
    int idx = blockIdx.x * 256 + threadIdx.x;
    int base = idx * 4;
    if (base >= NN * DD) return;
    int c = base & (DD - 1);
    floatx4 v = *(const floatx4*)(h2 + base);
    floatx4 sc = *(const floatx4*)(scale2 + c);
    floatx4 sh = *(const floatx4*)(shift2 + c);
    floatx4 o;
#pragma unroll
    for (int j = 0; j < 4; ++j) o[j] = fmaxf(v[j] * sc[j] + sh[j], 0.f);
    *(floatx4*)(out + base) = o;
}

extern "C" void kernel_launch(void* const* d_in, const int* in_sizes, int n_in,
                              void* d_out, int out_size, void* d_ws, size_t ws_size,
                              hipStream_t stream) {
    const float* x     = (const float*)d_in[0];
    const int*   ei    = (const int*)d_in[1];
    const float* ea    = (const float*)d_in[2];
    const float* We    = (const float*)d_in[3];
    const float* be    = (const float*)d_in[4];
    const float* W1    = (const float*)d_in[5];
    const float* b1    = (const float*)d_in[6];
    const float* g1    = (const float*)d_in[7];
    const float* beta1 = (const float*)d_in[8];
    const float* W2    = (const float*)d_in[9];
    const float* b2    = (const float*)d_in[10];
    const float* g2    = (const float*)d_in[11];
    const float* beta2 = (const float*)d_in[12];
    const float* epsp  = (const float*)d_in[13];

    // ws layout (floats unless noted); total ~234.4 MB
    float* ws      = (float*)d_ws;
    float* gsum1   = ws + 0;
    float* gsq1    = ws + 256;
    float* gsum2   = ws + 512;
    float* gsq2    = ws + 640;
    float* scale1  = ws + 768;
    float* shift1  = ws + 1024;
    float* scale2  = ws + 1280;
    float* shift2  = ws + 1408;
    uint32_t* deg     = (uint32_t*)(ws + 1536);   // 50176
    uint32_t* basep   = deg + 50176;              // 50176
    uint32_t* cursor  = basep + 50176;            // 50176
    uint32_t* partial = cursor + 50176;           // 256
    uint32_t* pos     = partial + 256;            // 800000
    float*    h       = (float*)(pos + EE);               // [NN*DD]
    uint16_t* msg     = (uint16_t*)(h + (size_t)NN * DD); // [EE*DD] bf16
    float*    t1      = (float*)msg;                      // aliased after msg dies
    float*    h2      = t1 + (size_t)NN * H1;
    short*    weswz   = (short*)(msg + (size_t)EE * DD);
    short*    w1swz   = weswz + 8192;
    short*    w2swz   = w1swz + 32768;

    // zero stats block (1536 f32) + deg (50176 u32) in one memset (~207 KB)
    hipMemsetAsync(ws, 0, (1536 + 50176) * sizeof(uint32_t), stream);

    swz_kernel<<<dim3(32), 256, 0, stream>>>(We, weswz, 2, 64, 8192);
    swz_kernel<<<dim3(128), 256, 0, stream>>>(W1, w1swz, 4, 128, 32768);
    swz_kernel<<<dim3(128), 256, 0, stream>>>(W2, w2swz, 8, 256, 32768);

    count_kernel<<<dim3(3125), 256, 0, stream>>>(ei, deg);
    scan1_kernel<<<dim3(196), 256, 0, stream>>>(deg, partial);
    scan2_kernel<<<dim3(1), 256, 0, stream>>>(partial);
    scan3_kernel<<<dim3(196), 256, 0, stream>>>(deg, partial, basep, cursor);
    pos_kernel<<<dim3(3125), 256, 0, stream>>>(ei, cursor, pos);

    edge_kernel<<<dim3(2500), 256, 0, stream>>>(x, ei, ea, weswz, be, pos, msg);
    reduce_kernel<<<dim3(12500), 256, 0, stream>>>(msg, basep, deg, x, epsp, h);

    gemm1_kernel<<<dim3(782), 256, 0, stream>>>(h, w1swz, b1, t1, gsum1, gsq1);
    finalize_kernel<<<dim3(1), 256, 0, stream>>>(gsum1, gsq1, g1, beta1, scale1, shift1, H1);

    gemm2_kernel<<<dim3(782), 256, 0, stream>>>(t1, scale1, shift1, w2swz, b2, h2, gsum2, gsq2);
    finalize_kernel<<<dim3(1), 128, 0, stream>>>(gsum2, gsq2, g2, beta2, scale2, shift2, DD);

    out_kernel<<<dim3(6250), 256, 0, stream>>>(h2, scale2, shift2, (float*)d_out);
}